// Round 1
// baseline (6135.317 us; speedup 1.0000x reference)
//
#include <hip/hip_runtime.h>

#define N_NODES 100000
#define N_EDGES 3200000
#define IN_DIM  128
#define HID     64
#define N_GRAPHS 256

// ---------- gcn_norm: deg = 1 (self loop) + segment_sum(ew, col); dis = rsqrt ----------
__global__ __launch_bounds__(256) void deg_init_kernel(float* deg) {
    int i = blockIdx.x * 256 + threadIdx.x;
    if (i < N_NODES) deg[i] = 1.0f;   // self-loop weight
}

__global__ __launch_bounds__(256) void deg_accum_kernel(const int* __restrict__ col,
                                                        const float* __restrict__ ew,
                                                        float* deg) {
    int e = blockIdx.x * 256 + threadIdx.x;
    if (e < N_EDGES) unsafeAtomicAdd(&deg[col[e]], ew[e]);
}

__global__ __launch_bounds__(256) void make_dis_kernel(float* deg) {
    int i = blockIdx.x * 256 + threadIdx.x;
    if (i < N_NODES) {
        float d = deg[i];
        deg[i] = d > 0.f ? 1.0f / sqrtf(fmaxf(d, 1e-30f)) : 0.f;
    }
}

// ---------- layer 1 GEMM: xl = x @ W1 ; agg init = self-loop msg = xl * dis^2 ----------
__global__ __launch_bounds__(256) void gemm1_kernel(const float* __restrict__ x,
                                                    const float* __restrict__ W1,
                                                    const float* __restrict__ dis,
                                                    float* __restrict__ xl,
                                                    float* __restrict__ agg) {
    __shared__ float sW[IN_DIM * HID];   // 32 KB
    __shared__ float sx[4][IN_DIM];      // 2 KB
    int tid = threadIdx.x;
    const float4* W4  = (const float4*)W1;
    float4*       sW4 = (float4*)sW;
    #pragma unroll
    for (int i = 0; i < 8; ++i) sW4[tid + 256 * i] = W4[tid + 256 * i];
    int r0 = blockIdx.x * 4;             // 25000 blocks * 4 rows = 100000 exact
    const float4* x4  = (const float4*)(x + (size_t)r0 * IN_DIM);
    float4*       sx4 = (float4*)&sx[0][0];
    if (tid < 128) sx4[tid] = x4[tid];
    __syncthreads();
    int lr = tid >> 6, c = tid & 63;
    int r = r0 + lr;
    float acc = 0.f;
    #pragma unroll 8
    for (int k = 0; k < IN_DIM; ++k) acc += sx[lr][k] * sW[k * HID + c];
    xl[(size_t)r * HID + c] = acc;
    float d = dis[r];
    agg[(size_t)r * HID + c] = acc * d * d;   // self-loop: norm = dis[i]*1*dis[i]
}

// ---------- edge scatter: agg[col] += xl[row] * (dis[row]*ew*dis[col]) ----------
// 16 lanes per edge, float4 channels per lane; grid is exact (E*16/256).
__global__ __launch_bounds__(256) void edge_agg_kernel(const int* __restrict__ row,
                                                       const int* __restrict__ col,
                                                       const float* __restrict__ ew,
                                                       const float* __restrict__ dis,
                                                       const float* __restrict__ xl,
                                                       float* agg) {
    int t  = blockIdx.x * 256 + threadIdx.x;
    int e  = t >> 4;
    int c0 = (t & 15) << 2;
    int r  = row[e], cc = col[e];
    float nrm = dis[r] * ew[e] * dis[cc];
    const float4 xv = *(const float4*)(xl + (size_t)r * HID + c0);
    float* dst = agg + (size_t)cc * HID + c0;
    unsafeAtomicAdd(dst + 0, xv.x * nrm);
    unsafeAtomicAdd(dst + 1, xv.y * nrm);
    unsafeAtomicAdd(dst + 2, xv.z * nrm);
    unsafeAtomicAdd(dst + 3, xv.w * nrm);
}

// ---------- layer 2 GEMM: h1 = relu(agg1 + b1); xl2 = h1 @ W2; agg2 init = xl2*dis^2 ----
// agg2 may alias agg1: each block reads only its own rows into LDS (barrier) before
// overwriting the same rows — no cross-block hazard.
__global__ __launch_bounds__(256) void gemm2_kernel(const float* agg1,
                                                    const float* __restrict__ W2,
                                                    const float* __restrict__ b1,
                                                    const float* __restrict__ dis,
                                                    float* __restrict__ xl2,
                                                    float* agg2) {
    __shared__ float sW[HID * HID];      // 16 KB
    __shared__ float sh[4][HID];
    int tid = threadIdx.x;
    const float4* W4  = (const float4*)W2;
    float4*       sW4 = (float4*)sW;
    #pragma unroll
    for (int i = 0; i < 4; ++i) sW4[tid + 256 * i] = W4[tid + 256 * i];
    int r0 = blockIdx.x * 4;
    int lr = tid >> 6, c = tid & 63;
    int r = r0 + lr;
    float v = agg1[(size_t)r * HID + c] + b1[c];
    sh[lr][c] = v > 0.f ? v : 0.f;
    __syncthreads();
    float acc = 0.f;
    #pragma unroll 8
    for (int k = 0; k < HID; ++k) acc += sh[lr][k] * sW[k * HID + c];
    xl2[(size_t)r * HID + c] = acc;
    float d = dis[r];
    agg2[(size_t)r * HID + c] = acc * d * d;
}

// ---------- pooling: pooled[batch[i]] += relu(agg2[i]+b2); cnt[batch[i]] += 1 ----------
__global__ __launch_bounds__(256) void pool_kernel(const float* __restrict__ agg2,
                                                   const float* __restrict__ b2,
                                                   const int* __restrict__ batch,
                                                   float* pooled, float* cnt) {
    int t  = blockIdx.x * 256 + threadIdx.x;
    int i  = t >> 4;
    int c0 = (t & 15) << 2;
    int g  = batch[i];
    float4 v = *(const float4*)(agg2 + (size_t)i * HID + c0);
    float4 b = *(const float4*)(b2 + c0);
    float* dst = pooled + g * HID + c0;
    unsafeAtomicAdd(dst + 0, fmaxf(v.x + b.x, 0.f));
    unsafeAtomicAdd(dst + 1, fmaxf(v.y + b.y, 0.f));
    unsafeAtomicAdd(dst + 2, fmaxf(v.z + b.z, 0.f));
    unsafeAtomicAdd(dst + 3, fmaxf(v.w + b.w, 0.f));
    if ((t & 15) == 0) unsafeAtomicAdd(&cnt[g], 1.0f);
}

// ---------- head: out[g] = (pooled[g]/cnt[g]) . Wc + bc ----------
__global__ __launch_bounds__(64) void final_kernel(const float* __restrict__ pooled,
                                                   const float* __restrict__ cnt,
                                                   const float* __restrict__ Wc,
                                                   const float* __restrict__ bc,
                                                   float* __restrict__ out) {
    int g = blockIdx.x, lane = threadIdx.x;
    float v = pooled[g * HID + lane] / fmaxf(cnt[g], 1.0f) * Wc[lane];
    #pragma unroll
    for (int o = 32; o > 0; o >>= 1) v += __shfl_down(v, o, 64);
    if (lane == 0) out[g] = v + bc[0];
}

extern "C" void kernel_launch(void* const* d_in, const int* in_sizes, int n_in,
                              void* d_out, int out_size, void* d_ws, size_t ws_size,
                              hipStream_t stream) {
    const float* x     = (const float*)d_in[0];
    const int*   ei    = (const int*)  d_in[1];
    const float* ew    = (const float*)d_in[2];
    const int*   batch = (const int*)  d_in[3];
    const float* W1    = (const float*)d_in[4];
    const float* b1    = (const float*)d_in[5];
    const float* W2    = (const float*)d_in[6];
    const float* b2    = (const float*)d_in[7];
    const float* Wc    = (const float*)d_in[8];
    const float* bc    = (const float*)d_in[9];
    float* out = (float*)d_out;

    const int* row = ei;             // ei[0,:]
    const int* col = ei + N_EDGES;   // ei[1,:]

    // workspace layout (floats): deg/dis [N pad] | bufA [N*64] | bufB [N*64] | pooled | cnt
    float* deg    = (float*)d_ws;
    float* bufA   = deg + 100352;                     // N rounded to 256
    float* bufB   = bufA + (size_t)N_NODES * HID;
    float* pooled = bufB + (size_t)N_NODES * HID;
    float* cnt    = pooled + N_GRAPHS * HID;

    hipMemsetAsync(pooled, 0, (N_GRAPHS * HID + N_GRAPHS) * sizeof(float), stream);

    deg_init_kernel <<<(N_NODES + 255) / 256, 256, 0, stream>>>(deg);
    deg_accum_kernel<<<(N_EDGES + 255) / 256, 256, 0, stream>>>(col, ew, deg);
    make_dis_kernel <<<(N_NODES + 255) / 256, 256, 0, stream>>>(deg);

    gemm1_kernel    <<<N_NODES / 4,  256, 0, stream>>>(x, W1, deg, bufA, bufB);
    edge_agg_kernel <<<N_EDGES / 16, 256, 0, stream>>>(row, col, ew, deg, bufA, bufB);

    gemm2_kernel    <<<N_NODES / 4,  256, 0, stream>>>(bufB, W2, b1, deg, bufA, bufB);
    edge_agg_kernel <<<N_EDGES / 16, 256, 0, stream>>>(row, col, ew, deg, bufA, bufB);

    pool_kernel     <<<(N_NODES * 16) / 256, 256, 0, stream>>>(bufB, b2, batch, pooled, cnt);
    final_kernel    <<<N_GRAPHS, 64, 0, stream>>>(pooled, cnt, Wc, bc, out);
}

// Round 2
// 959.927 us; speedup vs baseline: 6.3914x; 6.3914x over previous
//
#include <hip/hip_runtime.h>

#define N_NODES 100000
#define N_PAD   100352        // 392*256
#define N_EDGES 3200000
#define IN_DIM  128
#define HID     64
#define N_GRAPHS 256

// ---------- init: deg = 1 (self loop), cnt = 0 ----------
__global__ __launch_bounds__(256) void init_kernel(float* deg, int* cnt) {
    int i = blockIdx.x * 256 + threadIdx.x;   // grid 392 covers N_PAD exactly
    deg[i] = 1.0f;
    cnt[i] = 0;
}

// ---------- histogram: cnt[col]++, deg[col] += ew ----------
__global__ __launch_bounds__(256) void hist_kernel(const int* __restrict__ col,
                                                   const float* __restrict__ ew,
                                                   int* cnt, float* deg) {
    int e = blockIdx.x * 256 + threadIdx.x;   // grid 12500 exact
    int c = col[e];
    atomicAdd(&cnt[c], 1);
    unsafeAtomicAdd(&deg[c], ew[e]);
}

__global__ __launch_bounds__(256) void make_dis_kernel(float* deg) {
    int i = blockIdx.x * 256 + threadIdx.x;
    if (i < N_NODES) {
        float d = deg[i];
        deg[i] = d > 0.f ? 1.0f / sqrtf(fmaxf(d, 1e-30f)) : 0.f;
    }
}

// ---------- exclusive scan of cnt (N_PAD elements), 2-level ----------
__global__ __launch_bounds__(256) void scan1_kernel(const int* __restrict__ cnt,
                                                    int* rowptr, int* bsum) {
    __shared__ int s[256];
    int i = blockIdx.x * 256 + threadIdx.x;
    int v = cnt[i];
    s[threadIdx.x] = v;
    __syncthreads();
    #pragma unroll
    for (int off = 1; off < 256; off <<= 1) {
        int t = (threadIdx.x >= off) ? s[threadIdx.x - off] : 0;
        __syncthreads();
        s[threadIdx.x] += t;
        __syncthreads();
    }
    rowptr[i] = s[threadIdx.x] - v;           // exclusive
    if (threadIdx.x == 255) bsum[blockIdx.x] = s[255];
}

__global__ __launch_bounds__(512) void scan2_kernel(const int* __restrict__ bsum, int* boff) {
    __shared__ int s[512];
    int v = (threadIdx.x < 392) ? bsum[threadIdx.x] : 0;
    s[threadIdx.x] = v;
    __syncthreads();
    #pragma unroll
    for (int off = 1; off < 512; off <<= 1) {
        int t = (threadIdx.x >= off) ? s[threadIdx.x - off] : 0;
        __syncthreads();
        s[threadIdx.x] += t;
        __syncthreads();
    }
    boff[threadIdx.x] = s[threadIdx.x] - v;   // exclusive
}

__global__ __launch_bounds__(256) void scan3_kernel(int* rowptr, const int* __restrict__ boff,
                                                    int* cursor) {
    int i = blockIdx.x * 256 + threadIdx.x;
    int r = rowptr[i] + boff[blockIdx.x];
    rowptr[i] = r;
    cursor[i] = r;
}

// ---------- scatter edges into CSR: csr[pos] = (row, dis[row]*ew*dis[col]) ----------
__global__ __launch_bounds__(256) void scatter_kernel(const int* __restrict__ row,
                                                      const int* __restrict__ col,
                                                      const float* __restrict__ ew,
                                                      const float* __restrict__ dis,
                                                      int* cursor, float2* __restrict__ csr) {
    int e = blockIdx.x * 256 + threadIdx.x;   // grid 12500 exact
    int c = col[e], r = row[e];
    float w = dis[r] * ew[e] * dis[c];
    int pos = atomicAdd(&cursor[c], 1);
    csr[pos] = make_float2(__int_as_float(r), w);
}

// ---------- layer 1 GEMM: xl = x @ W1 ----------
__global__ __launch_bounds__(256) void gemm1_kernel(const float* __restrict__ x,
                                                    const float* __restrict__ W1,
                                                    float* __restrict__ xl) {
    __shared__ float sW[IN_DIM * HID];   // 32 KB
    __shared__ float sx[4][IN_DIM];      // 2 KB
    int tid = threadIdx.x;
    const float4* W4  = (const float4*)W1;
    float4*       sW4 = (float4*)sW;
    #pragma unroll
    for (int i = 0; i < 8; ++i) sW4[tid + 256 * i] = W4[tid + 256 * i];
    int r0 = blockIdx.x * 4;             // 25000 blocks exact
    const float4* x4  = (const float4*)(x + (size_t)r0 * IN_DIM);
    float4*       sx4 = (float4*)&sx[0][0];
    if (tid < 128) sx4[tid] = x4[tid];
    __syncthreads();
    int lr = tid >> 6, c = tid & 63;
    float acc = 0.f;
    #pragma unroll 8
    for (int k = 0; k < IN_DIM; ++k) acc += sx[lr][k] * sW[k * HID + c];
    xl[(size_t)(r0 + lr) * HID + c] = acc;
}

// ---------- gather aggregation: agg[n] = xl[n]*dis[n]^2 + sum_in csr ----------
// one wave per node; 4 quarters x 16 lanes x float4 = 4 edges in flight
__global__ __launch_bounds__(256) void gather_kernel(const float2* __restrict__ csr,
                                                     const int* __restrict__ rowptr,
                                                     const float* __restrict__ dis,
                                                     const float* __restrict__ xl,
                                                     float* __restrict__ agg) {
    int n    = (blockIdx.x * 256 + threadIdx.x) >> 6;   // 25000 blocks * 4 waves = N exact
    int lane = threadIdx.x & 63;
    int q    = lane >> 4;
    int c0   = (lane & 15) << 2;
    int base = rowptr[n], end = rowptr[n + 1];
    float4 acc = make_float4(0.f, 0.f, 0.f, 0.f);
    if (q == 0) {
        float d  = dis[n];
        float d2 = d * d;
        float4 xs = *(const float4*)(xl + (size_t)n * HID + c0);
        acc = make_float4(xs.x * d2, xs.y * d2, xs.z * d2, xs.w * d2);
    }
    for (int j = base + q; j < end; j += 4) {
        float2 e = csr[j];
        int   r  = __float_as_int(e.x);
        float w  = e.y;
        float4 xv = *(const float4*)(xl + (size_t)r * HID + c0);
        acc.x += xv.x * w; acc.y += xv.y * w;
        acc.z += xv.z * w; acc.w += xv.w * w;
    }
    // reduce quarters: +32 then +16
    acc.x += __shfl_down(acc.x, 32, 64); acc.y += __shfl_down(acc.y, 32, 64);
    acc.z += __shfl_down(acc.z, 32, 64); acc.w += __shfl_down(acc.w, 32, 64);
    acc.x += __shfl_down(acc.x, 16, 64); acc.y += __shfl_down(acc.y, 16, 64);
    acc.z += __shfl_down(acc.z, 16, 64); acc.w += __shfl_down(acc.w, 16, 64);
    if (lane < 16) *(float4*)(agg + (size_t)n * HID + c0) = acc;
}

// ---------- layer 2 GEMM: xl2 = relu(agg1 + b1) @ W2 ----------
__global__ __launch_bounds__(256) void gemm2_kernel(const float* __restrict__ agg1,
                                                    const float* __restrict__ W2,
                                                    const float* __restrict__ b1,
                                                    float* __restrict__ xl2) {
    __shared__ float sW[HID * HID];      // 16 KB
    __shared__ float sh[4][HID];
    int tid = threadIdx.x;
    const float4* W4  = (const float4*)W2;
    float4*       sW4 = (float4*)sW;
    #pragma unroll
    for (int i = 0; i < 4; ++i) sW4[tid + 256 * i] = W4[tid + 256 * i];
    int r0 = blockIdx.x * 4;
    int lr = tid >> 6, c = tid & 63;
    float v = agg1[(size_t)(r0 + lr) * HID + c] + b1[c];
    sh[lr][c] = v > 0.f ? v : 0.f;
    __syncthreads();
    float acc = 0.f;
    #pragma unroll 8
    for (int k = 0; k < HID; ++k) acc += sh[lr][k] * sW[k * HID + c];
    xl2[(size_t)(r0 + lr) * HID + c] = acc;
}

// ---------- pooling + head: out[g] = mean_i relu(agg2[i]+b2) . Wc + bc ----------
// batch is sorted -> each graph is a contiguous node range; binary search it.
__global__ __launch_bounds__(256) void pool_head_kernel(const float* __restrict__ agg2,
                                                        const float* __restrict__ b2,
                                                        const int* __restrict__ batch,
                                                        const float* __restrict__ Wc,
                                                        const float* __restrict__ bc,
                                                        float* __restrict__ out) {
    int g = blockIdx.x;
    int lo = 0, hi = N_NODES;
    while (lo < hi) { int m = (lo + hi) >> 1; if (batch[m] < g) lo = m + 1; else hi = m; }
    int start = lo;
    hi = N_NODES;
    while (lo < hi) { int m = (lo + hi) >> 1; if (batch[m] < g + 1) lo = m + 1; else hi = m; }
    int end = lo;
    int w = threadIdx.x >> 6, lane = threadIdx.x & 63;
    float bb = b2[lane];
    float acc = 0.f;
    for (int i = start + w; i < end; i += 4) {
        float v = agg2[(size_t)i * HID + lane] + bb;
        acc += v > 0.f ? v : 0.f;
    }
    __shared__ float s[4][HID];
    s[w][lane] = acc;
    __syncthreads();
    if (w == 0) {
        float p = s[0][lane] + s[1][lane] + s[2][lane] + s[3][lane];
        float cntf = (float)(end - start);
        p = p / fmaxf(cntf, 1.0f) * Wc[lane];
        #pragma unroll
        for (int o = 32; o > 0; o >>= 1) p += __shfl_down(p, o, 64);
        if (lane == 0) out[g] = p + bc[0];
    }
}

extern "C" void kernel_launch(void* const* d_in, const int* in_sizes, int n_in,
                              void* d_out, int out_size, void* d_ws, size_t ws_size,
                              hipStream_t stream) {
    const float* x     = (const float*)d_in[0];
    const int*   ei    = (const int*)  d_in[1];
    const float* ew    = (const float*)d_in[2];
    const int*   batch = (const int*)  d_in[3];
    const float* W1    = (const float*)d_in[4];
    const float* b1    = (const float*)d_in[5];
    const float* W2    = (const float*)d_in[6];
    const float* b2    = (const float*)d_in[7];
    const float* Wc    = (const float*)d_in[8];
    const float* bc    = (const float*)d_in[9];
    float* out = (float*)d_out;

    const int* row = ei;             // ei[0,:]
    const int* col = ei + N_EDGES;   // ei[1,:]

    // workspace layout
    float*  deg    = (float*)d_ws;                 // N_PAD
    int*    rowptr = (int*)(deg + N_PAD);          // N_PAD
    int*    cursor = rowptr + N_PAD;               // N_PAD
    int*    cnt    = cursor + N_PAD;               // N_PAD
    int*    bsum   = cnt + N_PAD;                  // 512
    int*    boff   = bsum + 512;                   // 512
    float2* csr    = (float2*)(boff + 512);        // E float2 (offset is 8B-aligned)
    float*  bufA   = (float*)(csr + N_EDGES);      // N*HID
    float*  bufB   = bufA + (size_t)N_NODES * HID; // N*HID

    init_kernel    <<<N_PAD / 256,    256, 0, stream>>>(deg, cnt);
    hist_kernel    <<<N_EDGES / 256,  256, 0, stream>>>(col, ew, cnt, deg);
    make_dis_kernel<<<(N_NODES+255)/256, 256, 0, stream>>>(deg);
    scan1_kernel   <<<N_PAD / 256,    256, 0, stream>>>(cnt, rowptr, bsum);
    scan2_kernel   <<<1,              512, 0, stream>>>(bsum, boff);
    scan3_kernel   <<<N_PAD / 256,    256, 0, stream>>>(rowptr, boff, cursor);
    scatter_kernel <<<N_EDGES / 256,  256, 0, stream>>>(row, col, ew, deg, cursor, csr);

    gemm1_kernel   <<<N_NODES / 4,    256, 0, stream>>>(x, W1, bufA);
    gather_kernel  <<<N_NODES / 4,    256, 0, stream>>>(csr, rowptr, deg, bufA, bufB);
    gemm2_kernel   <<<N_NODES / 4,    256, 0, stream>>>(bufB, W2, b1, bufA);
    gather_kernel  <<<N_NODES / 4,    256, 0, stream>>>(csr, rowptr, deg, bufA, bufB);
    pool_head_kernel<<<N_GRAPHS,      256, 0, stream>>>(bufB, b2, batch, Wc, bc, out);
}